// Round 9
// baseline (425.728 us; speedup 1.0000x reference)
//
#include <hip/hip_runtime.h>
#include <stdint.h>

// Problem constants (fixed shapes)
#define DIMX 4096
#define NH   32
#define NKV  8
#define HD   128
#define SEQ  2048
#define QKVD 6144   // 4096 q + 1024 k + 1024 v

typedef _Float16 h16;
typedef __attribute__((ext_vector_type(8))) _Float16 h16x8;
typedef __attribute__((ext_vector_type(4))) _Float16 h16x4;
typedef __attribute__((ext_vector_type(4))) float   f32x4;

__device__ __forceinline__ void gload_lds16(const void* g, void* l) {
  __builtin_amdgcn_global_load_lds(
      (const __attribute__((address_space(1))) void*)g,
      (__attribute__((address_space(3))) void*)l, 16, 0, 0);
}

// ---- 16-lane reductions on the VALU via DPP reversal butterflies (no LDS pipe) ----
template <int CTRL>
__device__ __forceinline__ float dpp_mv(float x) {
  int y = __builtin_amdgcn_mov_dpp(__builtin_bit_cast(int, x), CTRL, 0xF, 0xF, true);
  return __builtin_bit_cast(float, y);
}
__device__ __forceinline__ float red16_max(float x) {
  x = fmaxf(x, dpp_mv<0xB1>(x));   // rev2
  x = fmaxf(x, dpp_mv<0x1B>(x));   // rev4
  x = fmaxf(x, dpp_mv<0x141>(x));  // rev8
  x = fmaxf(x, dpp_mv<0x140>(x));  // rev16
  return x;
}
__device__ __forceinline__ float red16_sum(float x) {
  x += dpp_mv<0xB1>(x);
  x += dpp_mv<0x1B>(x);
  x += dpp_mv<0x141>(x);
  x += dpp_mv<0x140>(x);
  return x;
}

// ---------- fused dequant (all 4 weights) + x cast ----------
// PERM=1 (q/k weights): permute out-feature rows so RoPE pairs (d, d+64) become
// adjacent interleaved columns (d' = 2*(d&63) | (d>>6)).  QK^T dot products are
// invariant under a shared per-head permutation of d, so flash_attn is unchanged.
template <int PERM>
__device__ __forceinline__ void dq_unit(const void* __restrict__ w, const float* __restrict__ sc,
                                        h16* __restrict__ out, int u, int flag) {
  uint32_t b4;
  if (flag) {
    const int4 t = *(const int4*)((const int*)w + 4 * u);
    b4 = (uint32_t)(t.x & 0xFF) | ((uint32_t)(t.y & 0xFF) << 8) |
         ((uint32_t)(t.z & 0xFF) << 16) | ((uint32_t)(t.w & 0xFF) << 24);
  } else {
    b4 = ((const uint32_t*)w)[u];
  }
  int r = u >> 4;
  int p = (u & 15) * 4;
  float shi = sc[2 * r], slo = sc[2 * r + 1];
  h16x4 hi, lo;
#pragma unroll
  for (int j = 0; j < 4; ++j) {
    int by = (int)((b4 >> (8 * j)) & 0xFF);
    int hn = (by << 24) >> 28;
    int ln = (by << 28) >> 28;
    hi[j] = (h16)((float)hn * shi);
    lo[j] = (h16)((float)ln * slo);
  }
  size_t base;
  if (PERM) {
    int row  = r >> 5;                                           // out-feature row
    int rowp = (row & ~127) | (((row & 63) << 1) | ((row >> 6) & 1));
    base = ((size_t)rowp << 12) + (size_t)((r & 31) << 7);
  } else {
    base = (size_t)r << 7;
  }
  *(h16x4*)(out + base + p)      = hi;
  *(h16x4*)(out + base + 64 + p) = lo;
}

#define U_WQ 2097152
#define U_WK 524288
#define U_WV 524288
#define U_WO 2097152

__global__ __launch_bounds__(256) void prep_all(
    const void* __restrict__ wq, const float* __restrict__ sq,
    const void* __restrict__ wk, const float* __restrict__ sk,
    const void* __restrict__ wv, const float* __restrict__ sv,
    const void* __restrict__ wo, const float* __restrict__ so,
    const float4* __restrict__ x,
    h16* __restrict__ Wqkv, h16* __restrict__ Wo, h16x4* __restrict__ xb) {
  __shared__ int sfl;
  if (threadIdx.x == 0) {
    int ok = 1;
    const int* wi = (const int*)wq;
    for (int i = 0; i < 64; ++i) {
      int v = wi[i];
      if (v < -128 || v > 127) ok = 0;
    }
    sfl = ok;
  }
  __syncthreads();
  const int fl = sfl;
  int u = blockIdx.x * 256 + threadIdx.x;
  if (u < U_WQ) { dq_unit<1>(wq, sq, Wqkv, u, fl); return; }
  u -= U_WQ;
  if (u < U_WK) { dq_unit<1>(wk, sk, Wqkv + 16777216, u, fl); return; }
  u -= U_WK;
  if (u < U_WV) { dq_unit<0>(wv, sv, Wqkv + 20971520, u, fl); return; }
  u -= U_WV;
  if (u < U_WO) { dq_unit<0>(wo, so, Wo, u, fl); return; }
  u -= U_WO;
  {
    float4 v = x[u];
    h16x4 o;
    o.x = (h16)v.x; o.y = (h16)v.y; o.z = (h16)v.z; o.w = (h16)v.w;
    xb[u] = o;
  }
}

// ---------- pipelined 256x(64*NT) GEMM, 256 blocks, 2 PHASES per K-tile ----------
// C[M,N] = A[M,K] @ B[N,K]^T.  8 waves 4M x 2N; wave tile 64 x (NT*32).
// phA(t): MFMA (a0,b0)+(a0,b1); reads LDA_(t,0)+LDA_(t,1)+LDB1_(t);
//         stages A0..3(t+1); vmcnt(4); barrier.
// phB(t): MFMA (a1,b1)+(a1,b0); reads LDB0_(t+1) [pre-read for next phA];
//         stages B(t+2); vmcnt(NB); barrier.
// LEDGER:
//  read coverage (every read's covering vmcnt >= 1 barrier earlier, all waves):
//   LDA_/LDB1_(t) @phA(t):  staged phA(t-1)/phB(t-2); drained WB(phB(t-1)) / WA(phA(t-1)).
//   LDB0_(t+1)   @phB(t):  staged phB(t-1); drained WA(phA(t)) [vmcnt(4) leaves A(t+1)].
//  write-after-read (every stage >= 1 barrier after target slot's reads drain):
//   STG A(t+1) @phA(t): tile t-1's af reads drained by end-phB(t-1). OK
//   STG B(t+2) @phB(t): LDB0_(t)/LDB1_(t) reads drain by end-phA(t). OK
//  waits (FIFO; loads/phase = 4 (phA) and NB (phB); NB = NT B-slots):
//   WA = vmcnt(4): drains B(t+1), leaves A(t+1).  WB = vmcnt(NB): drains A(t+1).
// NO XCD swizzle (r8 lesson): natural round-robin puts blocks with x%8==c on XCD c,
// so each XCD exclusively owns 4 B-panels (B read from HBM exactly once) and shares
// A via L3.  The r8 panel-per-XCD swizzle made every XCD stream ALL of B: FETCH
// 94MB -> 205MB.  Reverted.
template <typename OutT, int NT, int MODE>
__global__ __launch_bounds__(512, 2) void gemm_pipe(
    const h16* __restrict__ A, const h16* __restrict__ B, OutT* __restrict__ C,
    int N, int K,
    const float* __restrict__ cosb, const float* __restrict__ sinb,
    h16* __restrict__ vt) {
  constexpr int NSLOT = 4 + NT;
  constexpr int BUFH  = NSLOT * 4096;               // h16 per buffer
  __shared__ __attribute__((aligned(16))) h16 SM[2 * BUFH];

  const int tid  = threadIdx.x;
  const int w    = tid >> 6, lane = tid & 63;
  const int wr   = w >> 1, wc = w & 1;              // 4M x 2N waves
  const int quad = lane >> 4, l15 = lane & 15;
  const int axr  = l15 & 7;
  const int m0 = blockIdx.y * 256, n0 = blockIdx.x * (NT * 64);

  const h16* Ab = A + (size_t)m0 * K;
  const h16* Bb = B + (size_t)n0 * K;
  const int srow = tid >> 3;                        // stage row within slot (0..63)
  const int sg8  = ((tid & 7) ^ (srow & 7)) * 8;    // pre-swizzled global k-chunk

  f32x4 acc[2][2][2][NT];                           // [a][b][mt][nt]
#pragma unroll
  for (int a = 0; a < 2; ++a)
#pragma unroll
    for (int b = 0; b < 2; ++b)
#pragma unroll
      for (int mt = 0; mt < 2; ++mt)
#pragma unroll
        for (int nt = 0; nt < NT; ++nt) acc[a][b][mt][nt] = (f32x4){0.f, 0.f, 0.f, 0.f};

  h16x8 af[2][2][2];                // [aset][mt][ks] — written phA(t), dead by phA(t+1)
  h16x8 bf1[NT][2];                 // written phA(t), dead by phA(t+1)
  h16x8 bf0E[NT][2], bf0O[NT][2];   // tile-parity E/O double buffer (written phB(t-1))

#define STG(sl_, tile_) do {                                                        \
    const h16* g_ = ((sl_) < 4) ? (Ab + (size_t)((sl_) * 64) * K)                   \
                                : (Bb + (size_t)(((sl_) - 4) * 64) * K);            \
    char* d_ = (char*)(SM + ((tile_) & 1) * BUFH + (sl_) * 4096);                   \
    gload_lds16(g_ + (size_t)srow * K + (tile_) * 64 + sg8, d_ + tid * 16);         \
  } while (0)

#define LDA_(tile_, a_) do {                                                        \
    const h16* s_ = SM + ((tile_) & 1) * BUFH + wr * 4096;                          \
    _Pragma("unroll") for (int mt = 0; mt < 2; ++mt)                                \
    _Pragma("unroll") for (int ks = 0; ks < 2; ++ks)                                \
      af[a_][mt][ks] = *(const h16x8*)&s_[((a_) * 32 + mt * 16 + l15) * 64 +        \
                                          (((ks * 4 + quad) ^ axr) * 8)];           \
  } while (0)

#define LDB1_(tile_) do {                                                           \
    const h16* s_ = SM + ((tile_) & 1) * BUFH + 16384;                              \
    _Pragma("unroll") for (int nt = 0; nt < NT; ++nt)                               \
    _Pragma("unroll") for (int ks = 0; ks < 2; ++ks)                                \
      bf1[nt][ks] = *(const h16x8*)&s_[(NT * 32 + wc * (NT * 16) + nt * 16 + l15) * 64 + \
                                       (((ks * 4 + quad) ^ axr) * 8)];              \
  } while (0)

#define LDB0_(tile_, D_) do {                                                       \
    const h16* s_ = SM + ((tile_) & 1) * BUFH + 16384;                              \
    _Pragma("unroll") for (int nt = 0; nt < NT; ++nt)                               \
    _Pragma("unroll") for (int ks = 0; ks < 2; ++ks)                                \
      D_[nt][ks] = *(const h16x8*)&s_[(wc * (NT * 16) + nt * 16 + l15) * 64 +       \
                                      (((ks * 4 + quad) ^ axr) * 8)];               \
  } while (0)

#define MMAB1(a_) do {                                                              \
    __builtin_amdgcn_s_setprio(1);                                                  \
    _Pragma("unroll") for (int mt = 0; mt < 2; ++mt)                                \
    _Pragma("unroll") for (int nt = 0; nt < NT; ++nt)                               \
    _Pragma("unroll") for (int ks = 0; ks < 2; ++ks)                                \
      acc[a_][1][mt][nt] = __builtin_amdgcn_mfma_f32_16x16x32_f16(                  \
          af[a_][mt][ks], bf1[nt][ks], acc[a_][1][mt][nt], 0, 0, 0);                \
    __builtin_amdgcn_s_setprio(0);                                                  \
  } while (0)

#define MMAB0(a_, D_) do {                                                          \
    __builtin_amdgcn_s_setprio(1);                                                  \
    _Pragma("unroll") for (int mt = 0; mt < 2; ++mt)                                \
    _Pragma("unroll") for (int nt = 0; nt < NT; ++nt)                               \
    _Pragma("unroll") for (int ks = 0; ks < 2; ++ks)                                \
      acc[a_][0][mt][nt] = __builtin_amdgcn_mfma_f32_16x16x32_f16(                  \
          af[a_][mt][ks], D_[nt][ks], acc[a_][0][mt][nt], 0, 0, 0);                 \
    __builtin_amdgcn_s_setprio(0);                                                  \
  } while (0)

#define CFENCE asm volatile("" ::: "memory")
#define BARX do { CFENCE; __builtin_amdgcn_s_barrier(); CFENCE; } while (0)
#define WA   asm volatile("s_waitcnt vmcnt(4)" ::: "memory")
#define WB do { if constexpr (NT == 3) asm volatile("s_waitcnt vmcnt(3)" ::: "memory"); \
                else                   asm volatile("s_waitcnt vmcnt(2)" ::: "memory"); } while (0)
#define VM0  asm volatile("s_waitcnt vmcnt(0)" ::: "memory")

  const int NTILE = K >> 6;
  const int NIT   = K >> 7;

  // ---- prologue: tile0 (A then B), then B(1); drain tile0, leave B(1) in flight ----
  STG(0, 0); STG(1, 0); STG(2, 0); STG(3, 0);
  STG(4, 0); STG(5, 0);
  if constexpr (NT == 3) STG(6, 0);
  STG(4, 1); STG(5, 1);
  if constexpr (NT == 3) STG(6, 1);
  WB;                                // vmcnt(NB): drains tile0's 4+NB, leaves B(1)
  BARX;                              // tile0 globally visible
  LDB0_(0, bf0E);                    // pre-read bf0 for phA(0)

  for (int i = 0; i < NIT; ++i) {
    const int t0 = 2 * i, t1 = 2 * i + 1;
    const int T2 = (t0 + 2 < NTILE) ? t0 + 2 : NTILE - 1;   // tail: benign restage
    const int T3 = (t1 + 2 < NTILE) ? t1 + 2 : NTILE - 1;
    // ========== tile t0 (bf0 cur = E) ==========
    // phA: all tile-t reads; stage A(t+1); MFMA (a0,b0)(a0,b1)
    LDA_(t0, 0); LDA_(t0, 1); LDB1_(t0);
    STG(0, t1); STG(1, t1); STG(2, t1); STG(3, t1);
    MMAB0(0, bf0E); MMAB1(0);
    WA; BARX;
    // phB: pre-read bf0(t+1); stage B(t+2); MFMA (a1,b1)(a1,b0)
    LDB0_(t1, bf0O);
    STG(4, T2); STG(5, T2);
    if constexpr (NT == 3) STG(6, T2);
    MMAB1(1); MMAB0(1, bf0E);
    WB; BARX;
    // ========== tile t1 (bf0 cur = O) ==========
    LDA_(t1, 0); LDA_(t1, 1); LDB1_(t1);
    STG(0, T2); STG(1, T2); STG(2, T2); STG(3, T2);
    MMAB0(0, bf0O); MMAB1(0);
    WA; BARX;
    LDB0_(T2, bf0E);
    STG(4, T3); STG(5, T3);
    if constexpr (NT == 3) STG(6, T3);
    MMAB1(1); MMAB0(1, bf0O);
    WB; BARX;
  }
  VM0;   // drain tail prefetch DMAs before LDS dealloc at wave exit

  if constexpr (MODE == 1) {
    // ---------- pure-register epilogue: RoPE (interleaved pairs) or V-transpose ----------
#pragma unroll
    for (int a = 0; a < 2; ++a)
#pragma unroll
      for (int b = 0; b < 2; ++b)
#pragma unroll
        for (int mt = 0; mt < 2; ++mt)
#pragma unroll
          for (int nt = 0; nt < NT; ++nt) {
            const int cb   = n0 + b * (NT * 32) + wc * (NT * 16) + nt * 16;
            const int row0 = m0 + wr * 64 + a * 32 + mt * 16 + quad * 4;
            if (cb >= 5120) {
              // V chunk: register transpose into vt[kv][d][s]
              const int dcol = cb + l15 - 5120;
              h16x4 vvv;
#pragma unroll
              for (int r = 0; r < 4; ++r) vvv[r] = (h16)acc[a][b][mt][nt][r];
              *(h16x4*)(vt + (size_t)dcol * SEQ + row0) = vvv;
            } else {
              // q/k chunk: RoPE with partner = lane^1 (interleaved-pair permutation).
              // q columns (cb<4096) additionally absorb 1/sqrt(HD) so flash skips it.
              const float qs = (cb < 4096) ? 0.08838834764831845f : 1.0f;
              const int col = cb + l15;
              const int j   = (col & 127) >> 1;
              const float sgn = (col & 1) ? 1.f : -1.f;
#pragma unroll
              for (int r = 0; r < 4; ++r) {
                float own = acc[a][b][mt][nt][r];
                float par = dpp_mv<0xB1>(own);               // quad_perm(1,0,3,2): lane^1
                float cc  = cosb[(size_t)(row0 + r) * 64 + j];
                float ss  = sinb[(size_t)(row0 + r) * 64 + j];
                C[(size_t)(row0 + r) * N + col] = (OutT)((own * cc + sgn * par * ss) * qs);
              }
            }
          }
  } else {
    // plain store
#pragma unroll
    for (int a = 0; a < 2; ++a)
#pragma unroll
      for (int b = 0; b < 2; ++b)
#pragma unroll
        for (int mt = 0; mt < 2; ++mt)
#pragma unroll
          for (int nt = 0; nt < NT; ++nt)
#pragma unroll
            for (int r = 0; r < 4; ++r) {
              int row = m0 + wr * 64 + a * 32 + mt * 16 + quad * 4 + r;
              int col = n0 + b * (NT * 32) + wc * (NT * 16) + nt * 16 + l15;
              C[(size_t)row * N + col] = (OutT)acc[a][b][mt][nt][r];
            }
  }
#undef STG
#undef LDA_
#undef LDB1_
#undef LDB0_
#undef MMAB1
#undef MMAB0
#undef CFENCE
#undef BARX
#undef WA
#undef WB
#undef VM0
}

// ---------- flash attention: block = (h, y), 128 q-rows, 4 waves x 32 rows, BK=64 ----------
// T14 async reg-staging (r6, measured win); head index XCD-swizzled so each XCD
// serves exactly one kv-head's K/V (512KB -> L2-resident per XCD).
__global__ __launch_bounds__(256, 2) void flash_attn(
    const h16* __restrict__ qkv, const h16* __restrict__ vt, h16* __restrict__ o_out) {
  __shared__ __attribute__((aligned(16))) h16 Ks[64 * 128];
  __shared__ __attribute__((aligned(16))) h16 Vts[128 * 64];
  __shared__ __attribute__((aligned(16))) h16 Ps[4][32 * 72];

  const int tid  = threadIdx.x;
  const int w    = tid >> 6, lane = tid & 63;
  const int quad = lane >> 4, l15 = lane & 15;
  const int hp   = blockIdx.x;
  const int h    = ((hp & 7) << 2) | (hp >> 3);    // XCD x hosts kv-head x
  const int y    = blockIdx.y;
  const int qt   = (y < 8) ? (15 - y) : (y - 8);   // balanced heavy/light pairing
  const int kv   = h >> 2;
  const int rowq = qt * 128 + w * 32;
  const h16* vtg = vt + (size_t)kv * HD * SEQ;

  h16x8 qf[2][4];
#pragma unroll
  for (int mt = 0; mt < 2; ++mt) {
    const h16* qrow = qkv + (size_t)(rowq + mt * 16 + l15) * QKVD + h * 128;
#pragma unroll
    for (int ks = 0; ks < 4; ++ks)
      qf[mt][ks] = *(const h16x8*)(qrow + ks * 32 + quad * 8);
  }

  f32x4 o[2][8];
#pragma unroll
  for (int mt = 0; mt < 2; ++mt)
#pragma unroll
    for (int i = 0; i < 8; ++i) o[mt][i] = (f32x4){0.f, 0.f, 0.f, 0.f};
  float mrow[2][4], lrow[2][4];
#pragma unroll
  for (int mt = 0; mt < 2; ++mt)
#pragma unroll
    for (int r = 0; r < 4; ++r) { mrow[mt][r] = -3e30f; lrow[mt][r] = 0.f; }
  h16* Psw = Ps[w];

  // staging registers for tile kt+1 (static indexing only)
  h16x8 kreg[4], vreg[4];
#define LOADT(k0_) do {                                                              \
    _Pragma("unroll") for (int i = 0; i < 4; ++i) {                                  \
      int c = i * 256 + tid; int key = c >> 4, d8s = c & 15;                         \
      kreg[i] = *(const h16x8*)(qkv + (size_t)((k0_) + key) * QKVD + 4096 +          \
                                kv * 128 + ((d8s ^ (key & 15)) * 8));                \
    }                                                                                \
    _Pragma("unroll") for (int i = 0; i < 4; ++i) {                                  \
      int c = i * 256 + tid; int d = c >> 3, p = c & 7;                              \
      vreg[i] = *(const h16x8*)(vtg + (size_t)d * SEQ + (k0_) + ((p ^ (d & 7)) * 8));\
    }                                                                                \
  } while (0)

  const int nkt = 2 * qt + 2;
  LOADT(0);                         // prologue: tile 0 -> regs
  for (int kt = 0; kt < nkt; ++kt) {
    const int k0 = kt * 64;
    __syncthreads();                // all waves done reading previous tile's LDS
    // reg -> LDS (compiler inserts the vmcnt wait on kreg/vreg here)
#pragma unroll
    for (int i = 0; i < 4; ++i) *(h16x8*)((char*)Ks + (i * 256 + tid) * 16) = kreg[i];
#pragma unroll
    for (int i = 0; i < 4; ++i) *(h16x8*)((char*)Vts + (i * 256 + tid) * 16) = vreg[i];
    __syncthreads();                // publish tile kt
    const int knx = (kt + 1 < nkt) ? (kt + 1) * 64 : k0;   // clamp: benign refetch
    LOADT(knx);                     // issue next tile's loads; drain under compute

    if (k0 <= rowq + 31) {
      float alpha[2][4];
      f32x4 s2[2][4];
#pragma unroll
      for (int nt = 0; nt < 4; ++nt) {
        int key = nt * 16 + l15;
        f32x4 a0 = (f32x4){0.f, 0.f, 0.f, 0.f};
        f32x4 a1 = (f32x4){0.f, 0.f, 0.f, 0.f};
#pragma unroll
        for (int ks = 0; ks < 4; ++ks) {
          int d8 = ks * 4 + quad;
          h16x8 kf = *(const h16x8*)&Ks[key * 128 + ((d8 ^ (key & 15)) * 8)];
          a0 = __builtin_amdgcn_mfma_f32_16x16x32_f16(qf[0][ks], kf, a0, 0, 0, 0);
          a1 = __builtin_amdgcn_mfma_f32_16x16x32_f16(qf[1][ks], kf, a1, 0, 0, 0);
        }
        s2[0][nt] = a0;
        s2[1][nt] = a1;
      }
      // ---- row maxima (mask only on diagonal tiles), defer-max decision ----
      const bool needmask = (k0 + 63 > rowq);      // wave-uniform
      float tm2[2][4];
      float need = -3e30f;
#pragma unroll
      for (int mt = 0; mt < 2; ++mt) {
#pragma unroll
        for (int r = 0; r < 4; ++r) {
          float tm = -3e30f;
          if (needmask) {
            int rowg = rowq + mt * 16 + quad * 4 + r;
#pragma unroll
            for (int nt = 0; nt < 4; ++nt) {
              float v = s2[mt][nt][r];
              if (k0 + nt * 16 + l15 > rowg) v = -3e30f;
              s2[mt][nt][r] = v;
              tm = fmaxf(tm, v);
            }
          } else {
#pragma unroll
            for (int nt = 0; nt < 4; ++nt) tm = fmaxf(tm, s2[mt][nt][r]);
          }
          tm = red16_max(tm);
          tm2[mt][r] = tm;
          need = fmaxf(need, tm - mrow[mt][r]);
        }
      }
      if (__any(need > 8.0f)) {       // T13: rescale only when max grew past THR
#pragma unroll
        for (int mt = 0; mt < 2; ++mt)
#pragma unroll
          for (int r = 0; r < 4; ++r) {
            float mnew = fmaxf(mrow[mt][r], tm2[mt][r]);
            alpha[mt][r] = __expf(mrow[mt][r] - mnew);
            mrow[mt][r] = mnew;
          }
#pragma unroll
        for (int mt = 0; mt < 2; ++mt)
#pragma unroll
          for (int on = 0; on < 8; ++on) {
            o[mt][on][0] *= alpha[mt][0]; o[mt][on][1] *= alpha[mt][1];
            o[mt][on][2] *= alpha[mt][2]; o[mt][on][3] *= alpha[mt][3];
          }
#pragma unroll
        for (int mt = 0; mt < 2; ++mt)
#pragma unroll
          for (int r = 0; r < 4; ++r) lrow[mt][r] *= alpha[mt][r];
      }
      // ---- exp + P store + row sums (P bounded by e^THR, fine in h16/f32) ----
#pragma unroll
      for (int mt = 0; mt < 2; ++mt) {
#pragma unroll
        for (int r = 0; r < 4; ++r) {
          float m = mrow[mt][r];
          float ps = 0.f;
#pragma unroll
          for (int nt = 0; nt < 4; ++nt) {
            float e = __expf(s2[mt][nt][r] - m);
            ps += e;
            Psw[(mt * 16 + quad * 4 + r) * 72 + nt * 16 + l15] = (h16)e;
          }
          ps = red16_sum(ps);
          lrow[mt][r] += ps;
        }
      }
      asm volatile("s_waitcnt lgkmcnt(0)" ::: "memory");
#pragma unroll
      for (int ks = 0; ks < 2; ++ks) {
        h16x8 pf0 = *(const h16x8*)&Psw[(0  + l15) * 72 + ks * 32 + quad * 8];
        h16x8 pf1 = *(const h16x8*)&Psw[(16 + l15) * 72 + ks * 32 + quad * 8];
        int k8 = ks * 4 + quad;
#pragma unroll
        for (int on = 0; on < 8; ++on) {
          int d = on * 16 + l15;
          h16x8 vf = *(const h16x8*)&Vts[d * 64 + ((k8 ^ (d & 7)) * 8)];
          o[0][on] = __builtin_amdgcn_mfma_f32_16x16x32_f16(pf0, vf, o[0][on], 0, 0, 0);
          o[1][on] = __builtin_amdgcn_mfma_f32_16x16x32_f16(pf1, vf, o[1][on], 0, 0, 0);
        }
      }
    }
  }
#undef LOADT
#pragma unroll
  for (int mt = 0; mt < 2; ++mt) {
    float linv[4];
#pragma unroll
    for (int r = 0; r < 4; ++r) linv[r] = 1.0f / lrow[mt][r];
#pragma unroll
    for (int on = 0; on < 8; ++on)
#pragma unroll
      for (int r = 0; r < 4; ++r) {
        int row = rowq + mt * 16 + quad * 4 + r;
        int col = h * 128 + on * 16 + l15;
        o_out[(size_t)row * DIMX + col] = (h16)(o[mt][on][r] * linv[r]);
      }
  }
}

extern "C" void kernel_launch(void* const* d_in, const int* in_sizes, int n_in,
                              void* d_out, int out_size, void* d_ws, size_t ws_size,
                              hipStream_t stream) {
  const float* x    = (const float*)d_in[0];
  const void*  wq   = d_in[1];
  const float* sq   = (const float*)d_in[2];
  const void*  wk   = d_in[3];
  const float* sk   = (const float*)d_in[4];
  const void*  wv   = d_in[5];
  const float* sv   = (const float*)d_in[6];
  const void*  wo   = d_in[7];
  const float* so   = (const float*)d_in[8];
  const float* cosb = (const float*)d_in[9];
  const float* sinb = (const float*)d_in[10];
  float* out = (float*)d_out;

  char* ws = (char*)d_ws;
  h16* Wqkv = (h16*)ws;                      // 6144*4096 h16 = 50331648 B
  h16* Wo   = (h16*)(ws + 50331648);         // 4096*4096 h16 = 33554432 B
  h16* xb   = (h16*)(ws + 83886080);         // x as h16; later attn_out
  h16* qkv  = (h16*)(ws + 100663296);        // 2048*6144 h16
  h16* vt   = (h16*)d_out;                   // vt scratch lives in d_out (dead until O-proj)

  // fused dequant (wq,wk: RoPE-pair-interleaved rows; wv,wo plain) + cast(x)
  prep_all<<<28672, 256, 0, stream>>>(wq, sq, wk, sk, wv, sv, wo, so,
                                      (const float4*)x, Wqkv, Wo, (h16x4*)xb);

  // qkv = x @ Wqkv^T, 256x192, 2-phase/K-tile schedule (no XCD swizzle),
  // fused register RoPE (q: +1/sqrt(HD)) + direct V-transpose
  gemm_pipe<h16, 3, 1><<<dim3(32, 8), 512, 0, stream>>>(
      xb, Wqkv, qkv, QKVD, DIMX, cosb, sinb, vt);

  // flash attention (T14 async reg-staging, kv-XCD swizzle) -> attn_out
  flash_attn<<<dim3(32, 16), 256, 0, stream>>>(qkv, vt, xb);

  // out = attn_out @ Wo^T, 256x128, 2-phase schedule (no XCD swizzle)
  gemm_pipe<float, 2, 0><<<dim3(32, 8), 512, 0, stream>>>(
      xb, Wo, out, DIMX, DIMX, cosb, sinb, vt);
}

// Round 10
// 414.015 us; speedup vs baseline: 1.0283x; 1.0283x over previous
//
#include <hip/hip_runtime.h>
#include <stdint.h>

// Problem constants (fixed shapes)
#define DIMX 4096
#define NH   32
#define NKV  8
#define HD   128
#define SEQ  2048
#define QKVD 6144   // 4096 q + 1024 k + 1024 v

typedef _Float16 h16;
typedef __attribute__((ext_vector_type(8))) _Float16 h16x8;
typedef __attribute__((ext_vector_type(4))) _Float16 h16x4;
typedef __attribute__((ext_vector_type(4))) float   f32x4;

__device__ __forceinline__ void gload_lds16(const void* g, void* l) {
  __builtin_amdgcn_global_load_lds(
      (const __attribute__((address_space(1))) void*)g,
      (__attribute__((address_space(3))) void*)l, 16, 0, 0);
}

// ---- 16-lane reductions on the VALU via DPP reversal butterflies (no LDS pipe) ----
template <int CTRL>
__device__ __forceinline__ float dpp_mv(float x) {
  int y = __builtin_amdgcn_mov_dpp(__builtin_bit_cast(int, x), CTRL, 0xF, 0xF, true);
  return __builtin_bit_cast(float, y);
}
__device__ __forceinline__ float red16_max(float x) {
  x = fmaxf(x, dpp_mv<0xB1>(x));   // rev2
  x = fmaxf(x, dpp_mv<0x1B>(x));   // rev4
  x = fmaxf(x, dpp_mv<0x141>(x));  // rev8
  x = fmaxf(x, dpp_mv<0x140>(x));  // rev16
  return x;
}
__device__ __forceinline__ float red16_sum(float x) {
  x += dpp_mv<0xB1>(x);
  x += dpp_mv<0x1B>(x);
  x += dpp_mv<0x141>(x);
  x += dpp_mv<0x140>(x);
  return x;
}

// ---------- fused dequant (all 4 weights) + x cast ----------
// PERM=1 (q/k weights): permute out-feature rows so RoPE pairs (d, d+64) become
// adjacent interleaved columns (d' = 2*(d&63) | (d>>6)).  QK^T dot products are
// invariant under a shared per-head permutation of d, so flash_attn is unchanged.
template <int PERM>
__device__ __forceinline__ void dq_unit(const void* __restrict__ w, const float* __restrict__ sc,
                                        h16* __restrict__ out, int u, int flag) {
  uint32_t b4;
  if (flag) {
    const int4 t = *(const int4*)((const int*)w + 4 * u);
    b4 = (uint32_t)(t.x & 0xFF) | ((uint32_t)(t.y & 0xFF) << 8) |
         ((uint32_t)(t.z & 0xFF) << 16) | ((uint32_t)(t.w & 0xFF) << 24);
  } else {
    b4 = ((const uint32_t*)w)[u];
  }
  int r = u >> 4;
  int p = (u & 15) * 4;
  float shi = sc[2 * r], slo = sc[2 * r + 1];
  h16x4 hi, lo;
#pragma unroll
  for (int j = 0; j < 4; ++j) {
    int by = (int)((b4 >> (8 * j)) & 0xFF);
    int hn = (by << 24) >> 28;
    int ln = (by << 28) >> 28;
    hi[j] = (h16)((float)hn * shi);
    lo[j] = (h16)((float)ln * slo);
  }
  size_t base;
  if (PERM) {
    int row  = r >> 5;                                           // out-feature row
    int rowp = (row & ~127) | (((row & 63) << 1) | ((row >> 6) & 1));
    base = ((size_t)rowp << 12) + (size_t)((r & 31) << 7);
  } else {
    base = (size_t)r << 7;
  }
  *(h16x4*)(out + base + p)      = hi;
  *(h16x4*)(out + base + 64 + p) = lo;
}

#define U_WQ 2097152
#define U_WK 524288
#define U_WV 524288
#define U_WO 2097152

__global__ __launch_bounds__(256) void prep_all(
    const void* __restrict__ wq, const float* __restrict__ sq,
    const void* __restrict__ wk, const float* __restrict__ sk,
    const void* __restrict__ wv, const float* __restrict__ sv,
    const void* __restrict__ wo, const float* __restrict__ so,
    const float4* __restrict__ x,
    h16* __restrict__ Wqkv, h16* __restrict__ Wo, h16x4* __restrict__ xb) {
  __shared__ int sfl;
  if (threadIdx.x == 0) {
    int ok = 1;
    const int* wi = (const int*)wq;
    for (int i = 0; i < 64; ++i) {
      int v = wi[i];
      if (v < -128 || v > 127) ok = 0;
    }
    sfl = ok;
  }
  __syncthreads();
  const int fl = sfl;
  int u = blockIdx.x * 256 + threadIdx.x;
  if (u < U_WQ) { dq_unit<1>(wq, sq, Wqkv, u, fl); return; }
  u -= U_WQ;
  if (u < U_WK) { dq_unit<1>(wk, sk, Wqkv + 16777216, u, fl); return; }
  u -= U_WK;
  if (u < U_WV) { dq_unit<0>(wv, sv, Wqkv + 20971520, u, fl); return; }
  u -= U_WV;
  if (u < U_WO) { dq_unit<0>(wo, so, Wo, u, fl); return; }
  u -= U_WO;
  {
    float4 v = x[u];
    h16x4 o;
    o.x = (h16)v.x; o.y = (h16)v.y; o.z = (h16)v.z; o.w = (h16)v.w;
    xb[u] = o;
  }
}

// ---------- pipelined 256x(64*NT) GEMM, 2 phases/K-tile, B-half clustering ----------
// C[M,N] = A[M,K] @ B[N,K]^T.  8 waves 4M x 2N.  KEY (r9 lesson): NO MFMA may
// consume a same-phase ds_read.  Clusters split by B-half:
//   phA(t): MMA0 = all-rows x b0 [32 MFMA NT3]  (af(t): read phB(t-1); bf0(t): read phA(t-1))
//   phB(t): MMA1 = all-rows x b1 [16 MFMA]      (af(t) held; bf1(t): read phA(t))
// Reads: phA: bf1(t) [first], bf0(t+1) [after MMA0, WAR on bf0];
//        phB: af(t+1) into af E/O buffer [before MMA1, safe].
// Slots: A 4x 2-parity (t&1); B0 (NT-1 slots) 3-parity (t%3); B1 (1 slot) 3-parity.
// LDS: NT3 136KB / NT2 112KB.  Stage plan: phA: B1(t+2); phB: A(t+2), B0(t+3).
// Ledger (FIFO-simulated, steady + t=0):
//   coverage: bf1(t) drained @WPA(t-1) (staged phA(t-2), 2-ph slack);
//             bf0(t+1) drained @WPB(t-1)... B0(t+1) staged phB(t-2), drained WPB(t-1)? ->
//             B0(t+2) drained @WPB(t) (staged phB(t-1), 1.5-ph slack), read phA(t+1) OK;
//             af(t+1): A(t+1) staged phB(t-1), drained @WPA(t) (1-ph slack, A is L2-hot).
//   W-after-R: STGB1@phA writes (t+2)%3 != t%3 read parity; STGA/STGB0@phB write slots
//   whose tenant reads drained before end-phA(t) (first consumption = MMA0@phA(t)).
//   waits: WPA = vmcnt(NT) leaves [B0(t+2),B1(t+2)]; WPB = vmcnt(7|6) leaves
//   [B1(t+2),A(t+2),B0(t+3)].  Tail clamps restage byte-identical data into the
//   slot already holding that tile (parity of clamped index == tenant parity).
// No XCD swizzle (r8: natural x%8 round-robin gives each XCD exclusive B-panels).
template <typename OutT, int NT, int MODE>
__global__ __launch_bounds__(512, 2) void gemm_pipe(
    const h16* __restrict__ A, const h16* __restrict__ B, OutT* __restrict__ C,
    int N, int K,
    const float* __restrict__ cosb, const float* __restrict__ sinb,
    h16* __restrict__ vt) {
  constexpr int B0SZ   = (NT == 3) ? 8192 : 4096;   // h16 per B0 parity
  constexpr int B0ROWS = (NT == 3) ? 128 : 64;
  constexpr int NB0    = (NT == 3) ? 4 : 2;         // bf0 frags per wave
  constexpr int B0BASE = 32768;
  constexpr int B1BASE = 32768 + 3 * B0SZ;
  constexpr int SMSZ   = B1BASE + 3 * 4096;
  __shared__ __attribute__((aligned(16))) h16 SM[SMSZ];

  const int tid  = threadIdx.x;
  const int w    = tid >> 6, lane = tid & 63;
  const int wr   = w >> 1, wc = w & 1;              // 4M x 2N waves
  const int quad = lane >> 4, l15 = lane & 15;
  const int axr  = l15 & 7;
  const int m0 = blockIdx.y * 256, n0 = blockIdx.x * (NT * 64);

  const h16* Ab = A + (size_t)m0 * K;
  const h16* Bb = B + (size_t)n0 * K;
  const int srow = tid >> 3;                        // stage row within slot (0..63)
  const int sg8  = ((tid & 7) ^ (srow & 7)) * 8;    // pre-swizzled global k-chunk

  f32x4 acc0[2][2][NB0];                            // [a][mt][nt] — b0 group
  f32x4 acc1[2][2][2];                              // b1 group
#pragma unroll
  for (int a = 0; a < 2; ++a)
#pragma unroll
    for (int mt = 0; mt < 2; ++mt) {
#pragma unroll
      for (int nt = 0; nt < NB0; ++nt) acc0[a][mt][nt] = (f32x4){0.f, 0.f, 0.f, 0.f};
#pragma unroll
      for (int nt = 0; nt < 2; ++nt)   acc1[a][mt][nt] = (f32x4){0.f, 0.f, 0.f, 0.f};
    }

  h16x8 afE[2][2][2], afO[2][2][2];   // af E/O by tile parity
  h16x8 bf0[NB0][2];                  // single-buffered (reload after consumption)
  h16x8 bf1[2][2];                    // single-buffered

#define STGA(sl_, tile_) gload_lds16(                                               \
    Ab + (size_t)((sl_) * 64 + srow) * K + (tile_) * 64 + sg8,                      \
    (char*)(SM + ((tile_) & 1) * 16384 + (sl_) * 4096) + tid * 16)
#define STGB0(sl_, tile_) gload_lds16(                                              \
    Bb + (size_t)((sl_) * 64 + srow) * K + (tile_) * 64 + sg8,                      \
    (char*)(SM + B0BASE + ((tile_) % 3) * B0SZ + (sl_) * 4096) + tid * 16)
#define STGB1(tile_) gload_lds16(                                                   \
    Bb + (size_t)(B0ROWS + srow) * K + (tile_) * 64 + sg8,                          \
    (char*)(SM + B1BASE + ((tile_) % 3) * 4096) + tid * 16)

#define LDAF(tile_, D_) do {                                                        \
    const h16* s_ = SM + ((tile_) & 1) * 16384;                                     \
    _Pragma("unroll") for (int a = 0; a < 2; ++a)                                   \
    _Pragma("unroll") for (int mt = 0; mt < 2; ++mt)                                \
    _Pragma("unroll") for (int ks = 0; ks < 2; ++ks)                                \
      D_[a][mt][ks] = *(const h16x8*)&s_[(wr * 64 + a * 32 + mt * 16 + l15) * 64 +  \
                                         (((ks * 4 + quad) ^ axr) * 8)];            \
  } while (0)

#define LDB0_(tile_) do {                                                           \
    const h16* s_ = SM + B0BASE + ((tile_) % 3) * B0SZ;                             \
    _Pragma("unroll") for (int nt = 0; nt < NB0; ++nt)                              \
    _Pragma("unroll") for (int ks = 0; ks < 2; ++ks)                                \
      bf0[nt][ks] = *(const h16x8*)&s_[(wc * (B0ROWS / 2) + nt * 16 + l15) * 64 +   \
                                       (((ks * 4 + quad) ^ axr) * 8)];              \
  } while (0)

#define LDB1_(tile_) do {                                                           \
    const h16* s_ = SM + B1BASE + ((tile_) % 3) * 4096;                             \
    _Pragma("unroll") for (int nt = 0; nt < 2; ++nt)                                \
    _Pragma("unroll") for (int ks = 0; ks < 2; ++ks)                                \
      bf1[nt][ks] = *(const h16x8*)&s_[(wc * 32 + nt * 16 + l15) * 64 +             \
                                       (((ks * 4 + quad) ^ axr) * 8)];              \
  } while (0)

#define MMA0(AF_) do {                                                              \
    __builtin_amdgcn_s_setprio(1);                                                  \
    _Pragma("unroll") for (int a = 0; a < 2; ++a)                                   \
    _Pragma("unroll") for (int mt = 0; mt < 2; ++mt)                                \
    _Pragma("unroll") for (int nt = 0; nt < NB0; ++nt)                              \
    _Pragma("unroll") for (int ks = 0; ks < 2; ++ks)                                \
      acc0[a][mt][nt] = __builtin_amdgcn_mfma_f32_16x16x32_f16(                     \
          AF_[a][mt][ks], bf0[nt][ks], acc0[a][mt][nt], 0, 0, 0);                   \
    __builtin_amdgcn_s_setprio(0);                                                  \
  } while (0)

#define MMA1(AF_) do {                                                              \
    __builtin_amdgcn_s_setprio(1);                                                  \
    _Pragma("unroll") for (int a = 0; a < 2; ++a)                                   \
    _Pragma("unroll") for (int mt = 0; mt < 2; ++mt)                                \
    _Pragma("unroll") for (int nt = 0; nt < 2; ++nt)                                \
    _Pragma("unroll") for (int ks = 0; ks < 2; ++ks)                                \
      acc1[a][mt][nt] = __builtin_amdgcn_mfma_f32_16x16x32_f16(                     \
          AF_[a][mt][ks], bf1[nt][ks], acc1[a][mt][nt], 0, 0, 0);                   \
    __builtin_amdgcn_s_setprio(0);                                                  \
  } while (0)

#define CFENCE asm volatile("" ::: "memory")
#define BARX do { CFENCE; __builtin_amdgcn_s_barrier(); CFENCE; } while (0)
#define WPRE do { if constexpr (NT == 3) asm volatile("s_waitcnt vmcnt(6)" ::: "memory"); \
                  else                   asm volatile("s_waitcnt vmcnt(5)" ::: "memory"); } while (0)
#define WPA  do { if constexpr (NT == 3) asm volatile("s_waitcnt vmcnt(3)" ::: "memory"); \
                  else                   asm volatile("s_waitcnt vmcnt(2)" ::: "memory"); } while (0)
#define WPB  do { if constexpr (NT == 3) asm volatile("s_waitcnt vmcnt(7)" ::: "memory"); \
                  else                   asm volatile("s_waitcnt vmcnt(6)" ::: "memory"); } while (0)
#define VM0  asm volatile("s_waitcnt vmcnt(0)" ::: "memory")
#define STGB0ALL(tile_) do { STGB0(0, tile_); if constexpr (NT == 3) STGB0(1, tile_); } while (0)
#define STGAALL(tile_)  do { STGA(0, tile_); STGA(1, tile_); STGA(2, tile_); STGA(3, tile_); } while (0)

  const int L = (K >> 6) - 1;        // last tile index

  // ---- prologue (steady-state relative order): A(0), B0(0), B0(1), B1(0), B1(1),
  //      A(1), B0(2); drain first 10 (A0,B0(0),B0(1),B1(0),B1(1)); pre-reads. ----
  STGAALL(0);
  STGB0ALL(0); STGB0ALL(1);
  STGB1(0); STGB1(1);
  STGAALL(1);
  STGB0ALL(2);
  WPRE;
  BARX;
  LDAF(0, afE);
  LDB0_(0);

  const int NIT = (K >> 6) >> 1;
  for (int i = 0; i < NIT; ++i) {
    const int t0 = 2 * i, t1 = 2 * i + 1;
    const int t0p2 = (t0 + 2 < L) ? t0 + 2 : L;    // clamps: data-identical restage
    const int t0p3 = (t0 + 3 < L) ? t0 + 3 : L;
    const int t1p1 = (t1 + 1 < L) ? t1 + 1 : L;    // clamped read: harmless
    const int t1p2 = (t1 + 2 < L) ? t1 + 2 : L;
    const int t1p3 = (t1 + 3 < L) ? t1 + 3 : L;
    // ===== tile t0 (af_cur = E) =====
    LDB1_(t0);                 // for phB(t0)
    MMA0(afE);                 // af(t0), bf0(t0): both read >=1 phase ago
    LDB0_(t0 + 1);             // for phA(t1); after MMA0 (WAR on bf0)
    STGB1(t0p2);
    WPA; BARX;                 // drains A(t0+1) -> covers LDAF below
    LDAF(t1, afO);             // af E/O: safe before MMA1
    MMA1(afE);                 // af(t0), bf1(t0)
    STGAALL(t0p2); STGB0ALL(t0p3);
    WPB; BARX;                 // drains B0(t0+2) -> covers next LDB0_
    // ===== tile t1 (af_cur = O) =====
    LDB1_(t1);
    MMA0(afO);
    LDB0_(t1p1);
    STGB1(t1p2);
    WPA; BARX;
    LDAF(t1p1, afE);
    MMA1(afO);
    STGAALL(t1p2); STGB0ALL(t1p3);
    WPB; BARX;
  }
  VM0;   // drain tail prefetch DMAs before LDS dealloc at wave exit

  // ---------- epilogue ----------
  if constexpr (MODE == 1) {
    // group0 (acc0): cols n0 + wc*64(NT3)/32(NT2) + nt*16;  group1 (acc1): cols
    // n0 + B0ROWS + wc*32 + nt*16.  RoPE (lane^1 pairs) for q/k, V-transpose else.
#define EPI1(ACC_, CB_) do {                                                        \
    const int cb   = (CB_);                                                         \
    const int row0 = m0 + wr * 64 + a * 32 + mt * 16 + quad * 4;                    \
    if (cb >= 5120) {                                                               \
      const int dcol = cb + l15 - 5120;                                             \
      h16x4 vvv;                                                                    \
      _Pragma("unroll") for (int r = 0; r < 4; ++r) vvv[r] = (h16)ACC_[r];          \
      *(h16x4*)(vt + (size_t)dcol * SEQ + row0) = vvv;                              \
    } else {                                                                        \
      const float qs = (cb < 4096) ? 0.08838834764831845f : 1.0f;                   \
      const int col = cb + l15;                                                     \
      const int j   = (col & 127) >> 1;                                             \
      const float sgn = (col & 1) ? 1.f : -1.f;                                     \
      _Pragma("unroll") for (int r = 0; r < 4; ++r) {                               \
        float own = ACC_[r];                                                        \
        float par = dpp_mv<0xB1>(own);                                              \
        float cc  = cosb[(size_t)(row0 + r) * 64 + j];                              \
        float ss  = sinb[(size_t)(row0 + r) * 64 + j];                              \
        C[(size_t)(row0 + r) * N + col] = (OutT)((own * cc + sgn * par * ss) * qs); \
      }                                                                             \
    }                                                                               \
  } while (0)
#pragma unroll
    for (int a = 0; a < 2; ++a)
#pragma unroll
      for (int mt = 0; mt < 2; ++mt) {
#pragma unroll
        for (int nt = 0; nt < NB0; ++nt)
          EPI1(acc0[a][mt][nt], n0 + wc * (B0ROWS / 2) + nt * 16);
#pragma unroll
        for (int nt = 0; nt < 2; ++nt)
          EPI1(acc1[a][mt][nt], n0 + B0ROWS + wc * 32 + nt * 16);
      }
#undef EPI1
  } else {
#pragma unroll
    for (int a = 0; a < 2; ++a)
#pragma unroll
      for (int mt = 0; mt < 2; ++mt) {
        const int row0 = m0 + wr * 64 + a * 32 + mt * 16 + quad * 4;
#pragma unroll
        for (int nt = 0; nt < NB0; ++nt)
#pragma unroll
          for (int r = 0; r < 4; ++r)
            C[(size_t)(row0 + r) * N + n0 + wc * (B0ROWS / 2) + nt * 16 + l15] =
                (OutT)acc0[a][mt][nt][r];
#pragma unroll
        for (int nt = 0; nt < 2; ++nt)
#pragma unroll
          for (int r = 0; r < 4; ++r)
            C[(size_t)(row0 + r) * N + n0 + B0ROWS + wc * 32 + nt * 16 + l15] =
                (OutT)acc1[a][mt][nt][r];
      }
  }
#undef STGA
#undef STGB0
#undef STGB1
#undef STGB0ALL
#undef STGAALL
#undef LDAF
#undef LDB0_
#undef LDB1_
#undef MMA0
#undef MMA1
#undef CFENCE
#undef BARX
#undef WPRE
#undef WPA
#undef WPB
#undef VM0
}

// ---------- flash attention: block = (h, y), 128 q-rows, 4 waves x 32 rows, BK=64 ----------
// T14 async reg-staging (r6, measured win).  kv-head XCD swizzle REVERTED (r9:
// never A/B'd; totals suggest a ~25us regression outside the GEMMs).
__global__ __launch_bounds__(256, 2) void flash_attn(
    const h16* __restrict__ qkv, const h16* __restrict__ vt, h16* __restrict__ o_out) {
  __shared__ __attribute__((aligned(16))) h16 Ks[64 * 128];
  __shared__ __attribute__((aligned(16))) h16 Vts[128 * 64];
  __shared__ __attribute__((aligned(16))) h16 Ps[4][32 * 72];

  const int tid  = threadIdx.x;
  const int w    = tid >> 6, lane = tid & 63;
  const int quad = lane >> 4, l15 = lane & 15;
  const int h    = blockIdx.x;
  const int y    = blockIdx.y;
  const int qt   = (y < 8) ? (15 - y) : (y - 8);   // balanced heavy/light pairing
  const int kv   = h >> 2;
  const int rowq = qt * 128 + w * 32;
  const h16* vtg = vt + (size_t)kv * HD * SEQ;

  h16x8 qf[2][4];
#pragma unroll
  for (int mt = 0; mt < 2; ++mt) {
    const h16* qrow = qkv + (size_t)(rowq + mt * 16 + l15) * QKVD + h * 128;
#pragma unroll
    for (int ks = 0; ks < 4; ++ks)
      qf[mt][ks] = *(const h16x8*)(qrow + ks * 32 + quad * 8);
  }

  f32x4 o[2][8];
#pragma unroll
  for (int mt = 0; mt < 2; ++mt)
#pragma unroll
    for (int i = 0; i < 8; ++i) o[mt][i] = (f32x4){0.f, 0.f, 0.f, 0.f};
  float mrow[2][4], lrow[2][4];
#pragma unroll
  for (int mt = 0; mt < 2; ++mt)
#pragma unroll
    for (int r = 0; r < 4; ++r) { mrow[mt][r] = -3e30f; lrow[mt][r] = 0.f; }
  h16* Psw = Ps[w];

  // staging registers for tile kt+1 (static indexing only)
  h16x8 kreg[4], vreg[4];
#define LOADT(k0_) do {                                                              \
    _Pragma("unroll") for (int i = 0; i < 4; ++i) {                                  \
      int c = i * 256 + tid; int key = c >> 4, d8s = c & 15;                         \
      kreg[i] = *(const h16x8*)(qkv + (size_t)((k0_) + key) * QKVD + 4096 +          \
                                kv * 128 + ((d8s ^ (key & 15)) * 8));                \
    }                                                                                \
    _Pragma("unroll") for (int i = 0; i < 4; ++i) {                                  \
      int c = i * 256 + tid; int d = c >> 3, p = c & 7;                              \
      vreg[i] = *(const h16x8*)(vtg + (size_t)d * SEQ + (k0_) + ((p ^ (d & 7)) * 8));\
    }                                                                                \
  } while (0)

  const int nkt = 2 * qt + 2;
  LOADT(0);                         // prologue: tile 0 -> regs
  for (int kt = 0; kt < nkt; ++kt) {
    const int k0 = kt * 64;
    __syncthreads();                // all waves done reading previous tile's LDS
    // reg -> LDS (compiler inserts the vmcnt wait on kreg/vreg here)
#pragma unroll
    for (int i = 0; i < 4; ++i) *(h16x8*)((char*)Ks + (i * 256 + tid) * 16) = kreg[i];
#pragma unroll
    for (int i = 0; i < 4; ++i) *(h16x8*)((char*)Vts + (i * 256 + tid) * 16) = vreg[i];
    __syncthreads();                // publish tile kt
    const int knx = (kt + 1 < nkt) ? (kt + 1) * 64 : k0;   // clamp: benign refetch
    LOADT(knx);                     // issue next tile's loads; drain under compute

    if (k0 <= rowq + 31) {
      float alpha[2][4];
      f32x4 s2[2][4];
#pragma unroll
      for (int nt = 0; nt < 4; ++nt) {
        int key = nt * 16 + l15;
        f32x4 a0 = (f32x4){0.f, 0.f, 0.f, 0.f};
        f32x4 a1 = (f32x4){0.f, 0.f, 0.f, 0.f};
#pragma unroll
        for (int ks = 0; ks < 4; ++ks) {
          int d8 = ks * 4 + quad;
          h16x8 kf = *(const h16x8*)&Ks[key * 128 + ((d8 ^ (key & 15)) * 8)];
          a0 = __builtin_amdgcn_mfma_f32_16x16x32_f16(qf[0][ks], kf, a0, 0, 0, 0);
          a1 = __builtin_amdgcn_mfma_f32_16x16x32_f16(qf[1][ks], kf, a1, 0, 0, 0);
        }
        s2[0][nt] = a0;
        s2[1][nt] = a1;
      }
      // ---- row maxima (mask only on diagonal tiles), defer-max decision ----
      const bool needmask = (k0 + 63 > rowq);      // wave-uniform
      float tm2[2][4];
      float need = -3e30f;
#pragma unroll
      for (int mt = 0; mt < 2; ++mt) {
#pragma unroll
        for (int r = 0; r < 4; ++r) {
          float tm = -3e30f;
          if (needmask) {
            int rowg = rowq + mt * 16 + quad * 4 + r;
#pragma unroll
            for (int nt = 0; nt < 4; ++nt) {
              float v = s2[mt][nt][r];
              if (k0 + nt * 16 + l15 > rowg) v = -3e30f;
              s2[mt][nt][r] = v;
              tm = fmaxf(tm, v);
            }
          } else {
#pragma unroll
            for (int nt = 0; nt < 4; ++nt) tm = fmaxf(tm, s2[mt][nt][r]);
          }
          tm = red16_max(tm);
          tm2[mt][r] = tm;
          need = fmaxf(need, tm - mrow[mt][r]);
        }
      }
      if (__any(need > 8.0f)) {       // T13: rescale only when max grew past THR
#pragma unroll
        for (int mt = 0; mt < 2; ++mt)
#pragma unroll
          for (int r = 0; r < 4; ++r) {
            float mnew = fmaxf(mrow[mt][r], tm2[mt][r]);
            alpha[mt][r] = __expf(mrow[mt][r] - mnew);
            mrow[mt][r] = mnew;
          }
#pragma unroll
        for (int mt = 0; mt < 2; ++mt)
#pragma unroll
          for (int on = 0; on < 8; ++on) {
            o[mt][on][0] *= alpha[mt][0]; o[mt][on][1] *= alpha[mt][1];
            o[mt][on][2] *= alpha[mt][2]; o[mt][on][3] *= alpha[mt][3];
          }
#pragma unroll
        for (int mt = 0; mt < 2; ++mt)
#pragma unroll
          for (int r = 0; r < 4; ++r) lrow[mt][r] *= alpha[mt][r];
      }
      // ---- exp + P store + row sums (P bounded by e^THR, fine in h16/f32) ----
#pragma unroll
      for (int mt = 0; mt < 2; ++mt) {
#pragma unroll
        for (int r = 0; r < 4; ++r) {
          float m = mrow[mt][r];
          float ps = 0.f;
#pragma unroll
          for (int nt = 0; nt < 4; ++nt) {
            float e = __expf(s2[mt][nt][r] - m);
            ps += e;
            Psw[(mt * 16 + quad * 4 + r) * 72 + nt * 16 + l15] = (h16)e;
          }
          ps = red16_sum(ps);
          lrow[mt][r] += ps;
        }
      }
      asm volatile("s_waitcnt lgkmcnt(0)" ::: "memory");
#pragma unroll
      for (int ks = 0; ks < 2; ++ks) {
        h16x8 pf0 = *(const h16x8*)&Psw[(0  + l15) * 72 + ks * 32 + quad * 8];
        h16x8 pf1 = *(const h16x8*)&Psw[(16 + l15) * 72 + ks * 32 + quad * 8];
        int k8 = ks * 4 + quad;
#pragma unroll
        for (int on = 0; on < 8; ++on) {
          int d = on * 16 + l15;
          h16x8 vf = *(const h16x8*)&Vts[d * 64 + ((k8 ^ (d & 7)) * 8)];
          o[0][on] = __builtin_amdgcn_mfma_f32_16x16x32_f16(pf0, vf, o[0][on], 0, 0, 0);
          o[1][on] = __builtin_amdgcn_mfma_f32_16x16x32_f16(pf1, vf, o[1][on], 0, 0, 0);
        }
      }
    }
  }
#undef LOADT
#pragma unroll
  for (int mt = 0; mt < 2; ++mt) {
    float linv[4];
#pragma unroll
    for (int r = 0; r < 4; ++r) linv[r] = 1.0f / lrow[mt][r];
#pragma unroll
    for (int on = 0; on < 8; ++on)
#pragma unroll
      for (int r = 0; r < 4; ++r) {
        int row = rowq + mt * 16 + quad * 4 + r;
        int col = h * 128 + on * 16 + l15;
        o_out[(size_t)row * DIMX + col] = (h16)(o[mt][on][r] * linv[r]);
      }
  }
}

extern "C" void kernel_launch(void* const* d_in, const int* in_sizes, int n_in,
                              void* d_out, int out_size, void* d_ws, size_t ws_size,
                              hipStream_t stream) {
  const float* x    = (const float*)d_in[0];
  const void*  wq   = d_in[1];
  const float* sq   = (const float*)d_in[2];
  const void*  wk   = d_in[3];
  const float* sk   = (const float*)d_in[4];
  const void*  wv   = d_in[5];
  const float* sv   = (const float*)d_in[6];
  const void*  wo   = d_in[7];
  const float* so   = (const float*)d_in[8];
  const float* cosb = (const float*)d_in[9];
  const float* sinb = (const float*)d_in[10];
  float* out = (float*)d_out;

  char* ws = (char*)d_ws;
  h16* Wqkv = (h16*)ws;                      // 6144*4096 h16 = 50331648 B
  h16* Wo   = (h16*)(ws + 50331648);         // 4096*4096 h16 = 33554432 B
  h16* xb   = (h16*)(ws + 83886080);         // x as h16; later attn_out
  h16* qkv  = (h16*)(ws + 100663296);        // 2048*6144 h16
  h16* vt   = (h16*)d_out;                   // vt scratch lives in d_out (dead until O-proj)

  // fused dequant (wq,wk: RoPE-pair-interleaved rows; wv,wo plain) + cast(x)
  prep_all<<<28672, 256, 0, stream>>>(wq, sq, wk, sk, wv, sv, wo, so,
                                      (const float4*)x, Wqkv, Wo, (h16x4*)xb);

  // qkv = x @ Wqkv^T, 256x192, B-half-clustered 2-phase schedule,
  // fused register RoPE (q: +1/sqrt(HD)) + direct V-transpose
  gemm_pipe<h16, 3, 1><<<dim3(32, 8), 512, 0, stream>>>(
      xb, Wqkv, qkv, QKVD, DIMX, cosb, sinb, vt);

  // flash attention (T14 async reg-staging) -> attn_out (reuse xb region)
  flash_attn<<<dim3(32, 16), 256, 0, stream>>>(qkv, vt, xb);

  // out = attn_out @ Wo^T, 256x128, same schedule
  gemm_pipe<float, 2, 0><<<dim3(32, 8), 512, 0, stream>>>(
      xb, Wo, out, DIMX, DIMX, cosb, sinb, vt);
}